// Round 7
// baseline (1538.454 us; speedup 1.0000x reference)
//
#include <hip/hip_runtime.h>

// VQ argmin: exact bit-level emulation of numpy fp32 reference:
//   A  = np.sum(flat*flat, axis=1)     (numpy pairwise-sum tree, fp32)
//   M2 = (2*flat) @ emb.T              (BLAS: sequential fp32 fma chain over d)
//   dist = (A - M2) + ee;  argmin_k (first-min ties)
// out: int32 [65536]
//
// R7: e moved from the SMEM path (un-pipelinable: OoO completion forces
// lgkmcnt(0) drain per consume -> ~65% VALU wall, R3/R4) to LDS ds_read
// (in-order, fine-grained lgkmcnt, co-issues with other waves' VALU).
// e-slab (64k x 256d = 64 KB) staged ONCE per kt-pass -> no steady-state
// barriers (R1/R2's wall). Rn=2 x KT=64: 256 VALU-cyc vs 192 LDS-cyc per dd.
// acc 128 in AGPRs; bounds(256,2) -> no spill (R6's disaster). z mult = 16.

#define D_DIM  256
#define K_DIM  1024
#define HW     4096
#define N_TOT  65536
#define NSPLIT 8
#define KSPL   (K_DIM / NSPLIT)   // 128
#define KT     64
#define NKT    (KSPL / KT)        // 2
#define F32MAX 3.402823466e38f

// ---- fused prep: [0,1024) pack epk; [1024,1028) ee; [1028,1284) A

__global__ void prep_kernel(const float* __restrict__ e, const float* __restrict__ z,
                            float* __restrict__ epk, float* __restrict__ ee,
                            float* __restrict__ A) {
#pragma clang fp contract(off)
    const int bid = blockIdx.x;
    const int tid = threadIdx.x;

    if (bid < 1024) {
        // epk[(g*256 + d)*64 + j] = 2*emb[k][d], g=k>>6, j=k&63
        // x2 exact (exponent shift); z*(2e) == (2z)*e bitwise.
        const int k = bid, d = tid;
        epk[((size_t)(k >> 6) * D_DIM + d) * KT + (k & 63)] = 2.0f * e[(size_t)k * D_DIM + d];
        return;
    }
    if (bid < 1028) {
        // ee[k]: numpy pairwise tree (two 128-blocks of 8 interleaved accs)
        const int k = (bid - 1024) * 256 + tid;
        const float* row = e + (size_t)k * D_DIM;
        float total = 0.0f;
        #pragma unroll
        for (int h = 0; h < 2; ++h) {
            const float* a = row + h * 128;
            float r[8];
            #pragma unroll
            for (int j = 0; j < 8; ++j) { float v = a[j]; r[j] = v * v; }
            #pragma unroll
            for (int i = 8; i < 128; i += 8) {
                #pragma unroll
                for (int j = 0; j < 8; ++j) { float v = a[i + j]; r[j] = r[j] + v * v; }
            }
            float s = ((r[0] + r[1]) + (r[2] + r[3])) + ((r[4] + r[5]) + (r[6] + r[7]));
            total = (h == 0) ? s : (total + s);
        }
        ee[k] = total;
        return;
    }
    {
        // A[n]: same tree over z (strided layout)
        const int n = (bid - 1028) * 256 + tid;
        const float* base = z + (size_t)(n >> 12) * D_DIM * HW + (n & (HW - 1));
        float total = 0.0f;
        #pragma unroll
        for (int h = 0; h < 2; ++h) {
            float r[8];
            #pragma unroll
            for (int j = 0; j < 8; ++j) {
                float v = base[(size_t)(h * 128 + j) * HW];
                r[j] = v * v;
            }
            #pragma unroll
            for (int i = 8; i < 128; i += 8) {
                #pragma unroll
                for (int j = 0; j < 8; ++j) {
                    float v = base[(size_t)(h * 128 + i + j) * HW];
                    r[j] = r[j] + v * v;
                }
            }
            float s = ((r[0] + r[1]) + (r[2] + r[3])) + ((r[4] + r[5]) + (r[6] + r[7]));
            total = (h == 0) ? s : (total + s);
        }
        A[n] = total;
    }
}

// ---- main: Rn=2 n/thread, e-slab in LDS (broadcast ds_read), z reg ping-pong

__launch_bounds__(256, 2)
__global__ void vq_main(const float* __restrict__ z, const float* __restrict__ epk,
                        const float* __restrict__ A, const float* __restrict__ ee,
                        float* __restrict__ pv, int* __restrict__ pk) {
#pragma clang fp contract(off)
    __shared__ __align__(16) float es[D_DIM * KT];   // 64 KB: [d][j]

    const int tid  = threadIdx.x;
    const int s    = blockIdx.x & (NSPLIT - 1);
    const int slab = blockIdx.x >> 3;            // 0..127, 512 n per slab
    const int n0   = slab * 512 + tid;
    const int n1   = n0 + 256;
    const int b    = n0 >> 12;                   // 512 | 4096: within one batch
    const float* __restrict__ zp0 = z + (size_t)b * D_DIM * HW + (n0 & (HW - 1));
    const float* __restrict__ zp1 = z + (size_t)b * D_DIM * HW + (n1 & (HW - 1));

    const float An0 = A[n0];
    const float An1 = A[n1];
    float best0 = F32MAX, best1 = F32MAX;
    int   bk0 = 0, bk1 = 0;

    // z ping-pong: 8 d's per half per n; (mod 256) wrap re-primes next pass
    float za0[8], za1[8], zb0[8], zb1[8];
    #pragma unroll
    for (int i = 0; i < 8; ++i) {
        za0[i] = zp0[(size_t)i * HW];
        za1[i] = zp1[(size_t)i * HW];
    }

    #pragma unroll 1
    for (int kt = 0; kt < NKT; ++kt) {
        // ---- stage this kt's e-slab: straight 64 KB copy, coalesced/conflict-free
        __syncthreads();   // readers of previous slab done
        {
            const float* __restrict__ eg = epk + (size_t)(2 * s + kt) * (D_DIM * KT);
            #pragma unroll
            for (int r = 0; r < 16; ++r) {
                const int f = (r * 256 + tid) * 4;
                *(float4*)&es[f] = *(const float4*)(eg + f);
            }
        }
        __syncthreads();

        float a0[KT], a1[KT];
        #pragma unroll
        for (int j = 0; j < KT; ++j) { a0[j] = 0.0f; a1[j] = 0.0f; }

        #pragma unroll 1
        for (int it = 0; it < 16; ++it) {
            const int base = it * 16;
            // prefetch z for d = base+8 .. base+15
            #pragma unroll
            for (int i = 0; i < 8; ++i) {
                const size_t idx = (size_t)((base + 8 + i) & (D_DIM - 1)) * HW;
                zb0[i] = zp0[idx];
                zb1[i] = zp1[idx];
            }
            // compute d = base .. base+7 (ascending: exact chain per (n,k))
            #pragma unroll
            for (int dd = 0; dd < 8; ++dd) {
                const float zv0 = za0[dd], zv1 = za1[dd];
                const float4* __restrict__ e4 = (const float4*)&es[(base + dd) * KT];
                #pragma unroll
                for (int q = 0; q < 16; ++q) {       // 16 broadcast ds_read_b128
                    const float4 ev = e4[q];
                    const int j = q * 4;
                    a0[j+0] = fmaf(zv0, ev.x, a0[j+0]);
                    a1[j+0] = fmaf(zv1, ev.x, a1[j+0]);
                    a0[j+1] = fmaf(zv0, ev.y, a0[j+1]);
                    a1[j+1] = fmaf(zv1, ev.y, a1[j+1]);
                    a0[j+2] = fmaf(zv0, ev.z, a0[j+2]);
                    a1[j+2] = fmaf(zv1, ev.z, a1[j+2]);
                    a0[j+3] = fmaf(zv0, ev.w, a0[j+3]);
                    a1[j+3] = fmaf(zv1, ev.w, a1[j+3]);
                }
            }
            // prefetch z for d = base+16 .. base+23 (mod 256: re-primes next pass)
            #pragma unroll
            for (int i = 0; i < 8; ++i) {
                const size_t idx = (size_t)((base + 16 + i) & (D_DIM - 1)) * HW;
                za0[i] = zp0[idx];
                za1[i] = zp1[idx];
            }
            // compute d = base+8 .. base+15
            #pragma unroll
            for (int dd = 0; dd < 8; ++dd) {
                const float zv0 = zb0[dd], zv1 = zb1[dd];
                const float4* __restrict__ e4 = (const float4*)&es[(base + 8 + dd) * KT];
                #pragma unroll
                for (int q = 0; q < 16; ++q) {
                    const float4 ev = e4[q];
                    const int j = q * 4;
                    a0[j+0] = fmaf(zv0, ev.x, a0[j+0]);
                    a1[j+0] = fmaf(zv1, ev.x, a1[j+0]);
                    a0[j+1] = fmaf(zv0, ev.y, a0[j+1]);
                    a1[j+1] = fmaf(zv1, ev.y, a1[j+1]);
                    a0[j+2] = fmaf(zv0, ev.z, a0[j+2]);
                    a1[j+2] = fmaf(zv1, ev.z, a1[j+2]);
                    a0[j+3] = fmaf(zv0, ev.w, a0[j+3]);
                    a1[j+3] = fmaf(zv1, ev.w, a1[j+3]);
                }
            }
        }

        // epilogue: dist = (An - M2) + ee; j ascending -> first-min ties
        const int kb = s * KSPL + kt * KT;
        #pragma unroll
        for (int j = 0; j < KT; ++j) {
            const int kg = kb + j;
            const float eev = ee[kg];
            const float d0 = (An0 - a0[j]) + eev;
            const float d1 = (An1 - a1[j]) + eev;
            if (d0 < best0) { best0 = d0; bk0 = kg; }
            if (d1 < best1) { best1 = d1; bk1 = kg; }
        }
    }

    pv[(size_t)s * N_TOT + n0] = best0;
    pk[(size_t)s * N_TOT + n0] = bk0;
    pv[(size_t)s * N_TOT + n1] = best1;
    pk[(size_t)s * N_TOT + n1] = bk1;
}

// ---- exact cross-split combine (s ascending = k ascending; strict < = first-min)

__global__ void combine_kernel(const float* __restrict__ pv, const int* __restrict__ pk,
                               int* __restrict__ out) {
    int n = blockIdx.x * blockDim.x + threadIdx.x;
    float bv = pv[n];
    int   bk = pk[n];
    #pragma unroll
    for (int s2 = 1; s2 < NSPLIT; ++s2) {
        float v = pv[(size_t)s2 * N_TOT + n];
        int   k = pk[(size_t)s2 * N_TOT + n];
        if (v < bv) { bv = v; bk = k; }
    }
    out[n] = bk;
}

extern "C" void kernel_launch(void* const* d_in, const int* in_sizes, int n_in,
                              void* d_out, int out_size, void* d_ws, size_t ws_size,
                              hipStream_t stream) {
    const float* z   = (const float*)d_in[0];   // [16,256,64,64]
    const float* emb = (const float*)d_in[1];   // [1024,256]
    int* out = (int*)d_out;                     // [65536] int32

    float* wsA   = (float*)d_ws;                    // 65536
    float* wsEE  = wsA + N_TOT;                     // 1024
    float* wsEPK = wsEE + K_DIM;                    // 262144
    float* wsPV  = wsEPK + (size_t)D_DIM * K_DIM;   // 8*65536
    int*   wsPK  = (int*)(wsPV + (size_t)NSPLIT * N_TOT);  // 8*65536

    prep_kernel<<<1284, 256, 0, stream>>>(emb, z, wsEPK, wsEE, wsA);
    vq_main<<<(N_TOT / 512) * NSPLIT, 256, 0, stream>>>(z, wsEPK, wsA, wsEE, wsPV, wsPK);
    combine_kernel<<<N_TOT / 256, 256, 0, stream>>>(wsPV, wsPK, out);
}